// Round 7
// baseline (318.335 us; speedup 1.0000x reference)
//
#include <hip/hip_runtime.h>

static constexpr float SCALE = 0.08838834764831845f; // 1/sqrt(128)

typedef __bf16 bf16;
typedef __bf16 bf16x8 __attribute__((ext_vector_type(8)));
typedef float  f32x4  __attribute__((ext_vector_type(4)));

#define MFMA16(a, b, c) __builtin_amdgcn_mfma_f32_16x16x32_bf16((a), (b), (c), 0, 0, 0)

__device__ inline bf16x8 cvt8(const float4& x, const float4& y) {
  bf16x8 r;
  r[0] = (bf16)x.x; r[1] = (bf16)x.y; r[2] = (bf16)x.z; r[3] = (bf16)x.w;
  r[4] = (bf16)y.x; r[5] = (bf16)y.y; r[6] = (bf16)y.z; r[7] = (bf16)y.w;
  return r;
}

// =====================================================================
// Batched projection GEMM (q,k,v in one launch; blockIdx.y selects).
// sel==0 (q): fp32 qf + bf16 q16 in [b,h,i,dk]
// sel==1 (k): bf16 k16 in [b,h,i,dk]
// sel==2 (v): bf16 vt16 TRANSPOSED [b,h,dk,i]
// =====================================================================
__global__ __launch_bounds__(256)
void proj3_mfma(const float* __restrict__ Aq, const float* __restrict__ Ak,
                const float* __restrict__ Av,
                const float* __restrict__ Wq, const float* __restrict__ Wk,
                const float* __restrict__ Wv,
                const float* __restrict__ bq, const float* __restrict__ bk,
                const float* __restrict__ bv,
                float* __restrict__ qf, bf16* __restrict__ q16,
                bf16* __restrict__ k16, bf16* __restrict__ vt16)
{
  const int sel = blockIdx.y;
  const float* A    = sel == 0 ? Aq : (sel == 1 ? Ak : Av);
  const float* W    = sel == 0 ? Wq : (sel == 1 ? Wk : Wv);
  const float* bias = sel == 0 ? bq : (sel == 1 ? bk : bv);

  __shared__ bf16 As[64][72];
  __shared__ bf16 Bs[64][72];
  const int t = threadIdx.x;
  const int m0 = (blockIdx.x >> 4) << 6;
  const int n0 = (blockIdx.x & 15) << 6;
  const int wave = t >> 6, lane = t & 63;
  const int wr = wave >> 1, wc = wave & 1;
  const int srow = t >> 2, skc = (t & 3) << 4;
  const float* Ap = A + (size_t)(m0 + srow) * 1024 + skc;
  const float* Wp = W + (size_t)(n0 + srow) * 1024 + skc;
  const int fr = lane & 15, kb = (lane >> 4) << 3;
  f32x4 acc[2][2];
#pragma unroll
  for (int i = 0; i < 2; ++i)
#pragma unroll
    for (int j = 0; j < 2; ++j) acc[i][j] = (f32x4){0.f, 0.f, 0.f, 0.f};

  float4 a4[4], w4[4], a4n[4], w4n[4];
#pragma unroll
  for (int u = 0; u < 4; ++u) {
    a4[u] = *(const float4*)(Ap + u * 4);
    w4[u] = *(const float4*)(Wp + u * 4);
  }
  for (int k0 = 0; k0 < 1024; k0 += 64) {
    __syncthreads();
    *(bf16x8*)&As[srow][skc]     = cvt8(a4[0], a4[1]);
    *(bf16x8*)&As[srow][skc + 8] = cvt8(a4[2], a4[3]);
    *(bf16x8*)&Bs[srow][skc]     = cvt8(w4[0], w4[1]);
    *(bf16x8*)&Bs[srow][skc + 8] = cvt8(w4[2], w4[3]);
    __syncthreads();
    if (k0 + 64 < 1024) {
#pragma unroll
      for (int u = 0; u < 4; ++u) {
        a4n[u] = *(const float4*)(Ap + k0 + 64 + u * 4);
        w4n[u] = *(const float4*)(Wp + k0 + 64 + u * 4);
      }
    }
#pragma unroll
    for (int ks = 0; ks < 2; ++ks) {
      bf16x8 af[2], bff[2];
#pragma unroll
      for (int f = 0; f < 2; ++f) {
        af[f]  = *(const bf16x8*)&As[wr * 32 + f * 16 + fr][ks * 32 + kb];
        bff[f] = *(const bf16x8*)&Bs[wc * 32 + f * 16 + fr][ks * 32 + kb];
      }
#pragma unroll
      for (int i = 0; i < 2; ++i)
#pragma unroll
        for (int j = 0; j < 2; ++j)
          acc[i][j] = MFMA16(af[i], bff[j], acc[i][j]);
    }
#pragma unroll
    for (int u = 0; u < 4; ++u) { a4[u] = a4n[u]; w4[u] = w4n[u]; }
  }
  const int lrow = (lane >> 4) << 2, lcol = lane & 15;
#pragma unroll
  for (int i = 0; i < 2; ++i) {
#pragma unroll
    for (int j = 0; j < 2; ++j) {
      const int n = n0 + wc * 32 + j * 16 + lcol;
      const float bvl = bias[n];
#pragma unroll
      for (int r = 0; r < 4; ++r) {
        const int m = m0 + wr * 32 + i * 16 + lrow + r;
        const float val = acc[i][j][r] + bvl;
        const int b = m >> 9, ii = m & 511, h = n >> 7, dk = n & 127;
        if (sel == 2) {
          vt16[(((size_t)(b * 8 + h) * 128) + dk) * 512 + ii] = (bf16)val;
        } else {
          const size_t idx = (((size_t)(b * 8 + h) * 512) + ii) * 128 + dk;
          if (sel == 0) { qf[idx] = val; q16[idx] = (bf16)val; }
          else          { k16[idx] = (bf16)val; }
        }
      }
    }
  }
}

// =====================================================================
// qs_fat: blocks 0..1023 = QK^T MFMA (sc = q16 @ k16^T, overwrite);
//         block 1024     = sep/gating/loss.
// =====================================================================
__global__ __launch_bounds__(256)
void qs_fat(const bf16* __restrict__ Q, const bf16* __restrict__ Kb,
            float* __restrict__ scores,
            const float* __restrict__ qf, const float* __restrict__ hw,
            const int* __restrict__ sep_id, const float* __restrict__ hreg,
            float* __restrict__ g, float* __restrict__ loss_out)
{
  __shared__ bf16 As[64][72];
  __shared__ bf16 Bs[64][72];
  __shared__ float pool[16][4];
  __shared__ float spred[16][4];
  __shared__ float lbuf[16];
  __shared__ int sids[4];
  const int t = threadIdx.x;

  if (blockIdx.x >= 1024) {
    if (t < 4) sids[t] = sep_id[t];
    __syncthreads();
    {
      const int dot = t >> 2, sub = t & 3;
      const int bh = dot >> 2, n = dot & 3;
      const int b = bh >> 3, h = bh & 7;
      const int row = sids[n];
      const float* qp = qf + (((size_t)(b * 8 + h) * 512) + row) * 128 + sub * 32;
      const float* wp = hw + h * 128 + sub * 32;
      float s = 0.f;
#pragma unroll
      for (int dd = 0; dd < 32; ++dd) s = fmaf(qp[dd], wp[dd], s);
      s += __shfl_xor(s, 1);
      s += __shfl_xor(s, 2);
      if (sub == 0) pool[bh][n] = s;
    }
    __syncthreads();
    if (t < 16) {
      float pv[4];
#pragma unroll
      for (int n = 0; n < 4; ++n) pv[n] = pool[t][n];
      float mx = fmaxf(fmaxf(pv[0], pv[1]), fmaxf(pv[2], pv[3]));
      float sum = 0.f;
#pragma unroll
      for (int n = 0; n < 4; ++n) { pv[n] = expf(pv[n] - mx); sum += pv[n]; }
      const float inv = 1.f / sum;
      float maxp = 0.f, l2 = 0.f;
#pragma unroll
      for (int n = 0; n < 4; ++n) {
        const float pr = pv[n] * inv;
        spred[t][n] = pr;
        maxp = fmaxf(maxp, pr);
        const float tg = hreg[n];
        l2 += tg * (logf(tg) - logf(pr));
      }
      lbuf[t] = (1.f - maxp) / 16.f + l2 / 64.f;
    }
    __syncthreads();
    if (t == 0) {
      float L = 0.f;
#pragma unroll
      for (int r = 0; r < 16; ++r) L += lbuf[r];
      loss_out[0] = L;
    }
    for (int idx = t; idx < 16 * 512; idx += 256) {
      const int bh = idx >> 9, pp = idx & 511;
      float gg = 0.f;
#pragma unroll
      for (int n = 0; n < 4; ++n)
        gg += spred[bh][n] * (pp >= sids[n] ? 1.f : 0.f);
      g[idx] = gg;
    }
    return;
  }

  const int bh = blockIdx.x >> 6, tile = blockIdx.x & 63;
  const bf16* A = Q  + (size_t)bh * (512 * 128);
  const bf16* B = Kb + (size_t)bh * (512 * 128);
  float* C = scores + (size_t)bh * (512 * 512);
  const int m0 = (tile >> 3) << 6, n0 = (tile & 7) << 6;
  const int wave = t >> 6, lane = t & 63;
  const int wr = wave >> 1, wc = wave & 1;
  const int srow = t >> 2, skc = (t & 3) << 4;
  const int fr = lane & 15, kb = (lane >> 4) << 3;
  f32x4 acc[2][2];
#pragma unroll
  for (int i = 0; i < 2; ++i)
#pragma unroll
    for (int j = 0; j < 2; ++j) acc[i][j] = (f32x4){0.f, 0.f, 0.f, 0.f};

  const bf16* ap = A + (size_t)(m0 + srow) * 128 + skc;
  const bf16* bp = B + (size_t)(n0 + srow) * 128 + skc;
  uint4 a0 = *(const uint4*)ap, a1 = *(const uint4*)(ap + 8);
  uint4 b0 = *(const uint4*)bp, b1 = *(const uint4*)(bp + 8);
  for (int k0 = 0; k0 < 128; k0 += 64) {
    __syncthreads();
    *(uint4*)&As[srow][skc]     = a0; *(uint4*)&As[srow][skc + 8] = a1;
    *(uint4*)&Bs[srow][skc]     = b0; *(uint4*)&Bs[srow][skc + 8] = b1;
    __syncthreads();
    if (k0 == 0) {
      a0 = *(const uint4*)(ap + 64); a1 = *(const uint4*)(ap + 72);
      b0 = *(const uint4*)(bp + 64); b1 = *(const uint4*)(bp + 72);
    }
#pragma unroll
    for (int ks = 0; ks < 2; ++ks) {
      bf16x8 af[2], bff[2];
#pragma unroll
      for (int f = 0; f < 2; ++f) {
        af[f]  = *(const bf16x8*)&As[wr * 32 + f * 16 + fr][ks * 32 + kb];
        bff[f] = *(const bf16x8*)&Bs[wc * 32 + f * 16 + fr][ks * 32 + kb];
      }
#pragma unroll
      for (int i = 0; i < 2; ++i)
#pragma unroll
        for (int j = 0; j < 2; ++j)
          acc[i][j] = MFMA16(af[i], bff[j], acc[i][j]);
    }
  }
  const int lrow = (lane >> 4) << 2, lcol = lane & 15;
#pragma unroll
  for (int i = 0; i < 2; ++i)
#pragma unroll
    for (int j = 0; j < 2; ++j)
#pragma unroll
      for (int r = 0; r < 4; ++r) {
        const int m = m0 + wr * 32 + i * 16 + lrow + r;
        const int n = n0 + wc * 32 + j * 16 + lcol;
        C[(size_t)m * 512 + n] = acc[i][j][r];
      }
}

// =====================================================================
// stream_attn: one block per (b,i).
//  phase 1: stream rk -> rel[h][j] (2 j per 4-lane group, q from LDS)
//  phase 2: softmax((sc+rel)*SCALE, mask, factor) -> pb16 + pj[j][12] LDS
//  phase 3: stream rv -> xa[b,i,h*128+d] = sum_j p[h,j]*rv[j,d]
// LDS aliasing: [qs|rel] -> pj -> red, barriers between.
// =====================================================================
__global__ __launch_bounds__(256)
void stream_attn(const float* __restrict__ qf, const float* __restrict__ rk,
                 const float* __restrict__ sc, const int* __restrict__ mask,
                 const float* __restrict__ g, const float* __restrict__ rv,
                 bf16* __restrict__ pb, float* __restrict__ xa)
{
  const int bi = blockIdx.x, b = bi >> 9, i = bi & 511;
  __shared__ float smem[6144];          // 24.6 KB, aliased by phase
  float* qs_  = smem;                   // [h][144]   (phase 0-1)
  float* rel_ = smem + 1152;            // [h][516]   (phase 1-2)
  float* pj_  = smem;                   // [j][12]    (phase 2-3)
  const int t = threadIdx.x;

  // phase 0: q row -> LDS
  {
    const int h = t >> 5, d0 = (t & 31) << 2;
    const int sub2 = d0 >> 5, dd = d0 & 31;
    const float4 qv = *(const float4*)&qf[(((size_t)(b * 8 + h) * 512) + i) * 128 + d0];
    *(float4*)&qs_[h * 144 + sub2 * 36 + dd] = qv;
  }
  __syncthreads();

  // phase 1: rel[h][j] = q[h].rk[j], 2 j per 4-lane group
  const int jj = t >> 2, sub = t & 3;
  for (int jp = 0; jp < 512; jp += 128) {
    const int j0 = jp + jj, j1 = j0 + 64;
    const float* rkp0 = rk + ((size_t)bi * 512 + j0) * 128 + sub * 32;
    const float* rkp1 = rk + ((size_t)bi * 512 + j1) * 128 + sub * 32;
    float rv0[32], rv1[32];
#pragma unroll
    for (int u = 0; u < 8; ++u) {
      *(float4*)&rv0[u * 4] = *(const float4*)&rkp0[u * 4];
      *(float4*)&rv1[u * 4] = *(const float4*)&rkp1[u * 4];
    }
    float ac0[8], ac1[8];
#pragma unroll
    for (int h = 0; h < 8; ++h) { ac0[h] = 0.f; ac1[h] = 0.f; }
#pragma unroll
    for (int d4 = 0; d4 < 8; ++d4) {
#pragma unroll
      for (int h = 0; h < 8; ++h) {
        const float4 qv = *(const float4*)&qs_[h * 144 + sub * 36 + (d4 << 2)];
        ac0[h] = fmaf(qv.x, rv0[d4*4+0], ac0[h]);
        ac0[h] = fmaf(qv.y, rv0[d4*4+1], ac0[h]);
        ac0[h] = fmaf(qv.z, rv0[d4*4+2], ac0[h]);
        ac0[h] = fmaf(qv.w, rv0[d4*4+3], ac0[h]);
        ac1[h] = fmaf(qv.x, rv1[d4*4+0], ac1[h]);
        ac1[h] = fmaf(qv.y, rv1[d4*4+1], ac1[h]);
        ac1[h] = fmaf(qv.z, rv1[d4*4+2], ac1[h]);
        ac1[h] = fmaf(qv.w, rv1[d4*4+3], ac1[h]);
      }
    }
#pragma unroll
    for (int h = 0; h < 8; ++h) {
      ac0[h] += __shfl_xor(ac0[h], 1);
      ac0[h] += __shfl_xor(ac0[h], 2);
      ac1[h] += __shfl_xor(ac1[h], 1);
      ac1[h] += __shfl_xor(ac1[h], 2);
    }
    const int h0 = sub << 1;
    rel_[h0 * 516 + j0]       = ac0[h0];
    rel_[(h0 + 1) * 516 + j0] = ac0[h0 + 1];
    rel_[h0 * 516 + j1]       = ac1[h0];
    rel_[(h0 + 1) * 516 + j1] = ac1[h0 + 1];
  }
  __syncthreads();

  // phase 2: softmax; p -> pb16 global (for pv) + pj LDS (for phase 3)
  {
    const int h = t >> 5, ln = t & 31;
    const float* scrow = sc + (((size_t)(b * 8 + h) * 512) + i) * 512;
    const int* mrow = mask + ((size_t)(b * 512 + i)) * 512;
    const float* grow = g + (b * 8 + h) * 512;
    const float gi = grow[i];
    float s[16];
    float mx = -3.402823466e+38f;
#pragma unroll
    for (int k = 0; k < 16; ++k) {
      const int j = ln + (k << 5);
      float sv = (scrow[j] + rel_[h * 516 + j]) * SCALE;
      if (mrow[j] == 0) sv = -1.0e9f;
      const float fac = (j >= i) ? gi : grow[j];
      sv *= fac;
      s[k] = sv;
      mx = fmaxf(mx, sv);
    }
    __syncthreads();   // all rel reads done; pj may overwrite
#pragma unroll
    for (int off = 16; off > 0; off >>= 1) mx = fmaxf(mx, __shfl_xor(mx, off));
    float sum = 0.f;
#pragma unroll
    for (int k = 0; k < 16; ++k) { const float e = __expf(s[k] - mx); s[k] = e; sum += e; }
#pragma unroll
    for (int off = 16; off > 0; off >>= 1) sum += __shfl_xor(sum, off);
    const float inv = 1.f / sum;
    bf16* prow = pb + (((size_t)(b * 8 + h) * 512) + i) * 512;
#pragma unroll
    for (int k = 0; k < 16; ++k) {
      const int j = ln + (k << 5);
      const float p = s[k] * inv;
      prow[j] = (bf16)p;
      pj_[j * 12 + h] = p;
    }
  }
  __syncthreads();

  // phase 3: xa[h][d] = sum_j p[h,j]*rv[j,d]; rv streamed once
  const int gq = t >> 5, ln3 = t & 31, d0 = ln3 << 2;
  f32x4 acc3[8];
#pragma unroll
  for (int h = 0; h < 8; ++h) acc3[h] = (f32x4){0.f, 0.f, 0.f, 0.f};
  const float* rp = rv + (size_t)bi * 512 * 128 + d0;
  for (int j = gq; j < 512; j += 8) {
    const float4 rr = *(const float4*)&rp[(size_t)j * 128];
    const f32x4 p0 = *(const f32x4*)&pj_[j * 12];      // h 0..3
    const f32x4 p1 = *(const f32x4*)&pj_[j * 12 + 4];  // h 4..7
#pragma unroll
    for (int e = 0; e < 4; ++e) {
      acc3[e][0] = fmaf(p0[e], rr.x, acc3[e][0]);
      acc3[e][1] = fmaf(p0[e], rr.y, acc3[e][1]);
      acc3[e][2] = fmaf(p0[e], rr.z, acc3[e][2]);
      acc3[e][3] = fmaf(p0[e], rr.w, acc3[e][3]);
      acc3[4+e][0] = fmaf(p1[e], rr.x, acc3[4+e][0]);
      acc3[4+e][1] = fmaf(p1[e], rr.y, acc3[4+e][1]);
      acc3[4+e][2] = fmaf(p1[e], rr.z, acc3[4+e][2]);
      acc3[4+e][3] = fmaf(p1[e], rr.w, acc3[4+e][3]);
    }
  }
  // combine gq pairs (0,1),(2,3),... within wave
#pragma unroll
  for (int h = 0; h < 8; ++h)
#pragma unroll
    for (int e = 0; e < 4; ++e) acc3[h][e] += __shfl_xor(acc3[h][e], 32);
  __syncthreads();   // pj dead; reuse smem as red[4][8][128]
  const int wv = t >> 6;
  if ((t & 63) < 32) {
#pragma unroll
    for (int h = 0; h < 8; ++h)
      *(f32x4*)&smem[(wv * 8 + h) * 128 + d0] = acc3[h];
  }
  __syncthreads();
  {
    const int h = t >> 5, dd = (t & 31) << 2;
    f32x4 r = (f32x4){0.f, 0.f, 0.f, 0.f};
#pragma unroll
    for (int w2 = 0; w2 < 4; ++w2) {
      const f32x4 v = *(const f32x4*)&smem[(w2 * 8 + h) * 128 + dd];
      r[0] += v[0]; r[1] += v[1]; r[2] += v[2]; r[3] += v[3];
    }
    *(f32x4*)&xa[((size_t)(b * 512 + i)) * 1024 + h * 128 + dd] = r;
  }
}

// =====================================================================
// PV MFMA: xb2[b,i,h*128+n] = p16[bh] @ vt16[bh] (W-form, K=512)
// =====================================================================
__global__ __launch_bounds__(256)
void pv_mfma(const bf16* __restrict__ P, const bf16* __restrict__ VT,
             float* __restrict__ x)
{
  const int bh = blockIdx.y, b = bh >> 3, h = bh & 7;
  const bf16* A = P  + (size_t)bh * (512 * 512);
  const bf16* B = VT + (size_t)bh * (128 * 512);
  float* C = x + (size_t)b * (512 * 1024) + h * 128;
  const int m0 = (blockIdx.x >> 1) << 6, n0 = (blockIdx.x & 1) << 6;
  __shared__ bf16 As[64][72];
  __shared__ bf16 Bs[64][72];
  const int t = threadIdx.x, wave = t >> 6, lane = t & 63;
  const int wr = wave >> 1, wc = wave & 1;
  const int srow = t >> 2, skc = (t & 3) << 4;
  const int fr = lane & 15, kb = (lane >> 4) << 3;
  f32x4 acc[2][2];
#pragma unroll
  for (int i = 0; i < 2; ++i)
#pragma unroll
    for (int j = 0; j < 2; ++j) acc[i][j] = (f32x4){0.f, 0.f, 0.f, 0.f};

  const bf16* ap = A + (size_t)(m0 + srow) * 512 + skc;
  const bf16* bp = B + (size_t)(n0 + srow) * 512 + skc;
  uint4 a0 = *(const uint4*)ap, a1 = *(const uint4*)(ap + 8);
  uint4 b0 = *(const uint4*)bp, b1 = *(const uint4*)(bp + 8);
  for (int k0 = 0; k0 < 512; k0 += 64) {
    __syncthreads();
    *(uint4*)&As[srow][skc]     = a0; *(uint4*)&As[srow][skc + 8] = a1;
    *(uint4*)&Bs[srow][skc]     = b0; *(uint4*)&Bs[srow][skc + 8] = b1;
    __syncthreads();
    if (k0 + 64 < 512) {
      a0 = *(const uint4*)(ap + k0 + 64); a1 = *(const uint4*)(ap + k0 + 72);
      b0 = *(const uint4*)(bp + k0 + 64); b1 = *(const uint4*)(bp + k0 + 72);
    }
#pragma unroll
    for (int ks = 0; ks < 2; ++ks) {
      bf16x8 af[2], bff[2];
#pragma unroll
      for (int f = 0; f < 2; ++f) {
        af[f]  = *(const bf16x8*)&As[wr * 32 + f * 16 + fr][ks * 32 + kb];
        bff[f] = *(const bf16x8*)&Bs[wc * 32 + f * 16 + fr][ks * 32 + kb];
      }
#pragma unroll
      for (int i = 0; i < 2; ++i)
#pragma unroll
        for (int j = 0; j < 2; ++j)
          acc[i][j] = MFMA16(af[i], bff[j], acc[i][j]);
    }
  }
  const int lrow = (lane >> 4) << 2, lcol = lane & 15;
#pragma unroll
  for (int i = 0; i < 2; ++i)
#pragma unroll
    for (int j = 0; j < 2; ++j)
#pragma unroll
      for (int r = 0; r < 4; ++r) {
        const int m = m0 + wr * 32 + i * 16 + lrow + r;
        const int n = n0 + wc * 32 + j * 16 + lcol;
        C[(size_t)m * 1024 + n] = acc[i][j][r];
      }
}

// =====================================================================
// Output projection: Cf[m*1024+n] = (xa + xb2) @ W^T + bias
// =====================================================================
__global__ __launch_bounds__(256)
void proj_out(const float* __restrict__ A, const float* __restrict__ A2,
              const float* __restrict__ W,
              const float* __restrict__ bias, float* __restrict__ Cf)
{
  __shared__ bf16 As[64][72];
  __shared__ bf16 Bs[64][72];
  const int t = threadIdx.x;
  const int m0 = (blockIdx.x >> 4) << 6;
  const int n0 = (blockIdx.x & 15) << 6;
  const int wave = t >> 6, lane = t & 63;
  const int wr = wave >> 1, wc = wave & 1;
  const int srow = t >> 2, skc = (t & 3) << 4;
  const float* Ap  = A  + (size_t)(m0 + srow) * 1024 + skc;
  const float* A2p = A2 + (size_t)(m0 + srow) * 1024 + skc;
  const float* Wp  = W  + (size_t)(n0 + srow) * 1024 + skc;
  const int fr = lane & 15, kb = (lane >> 4) << 3;
  f32x4 acc[2][2];
#pragma unroll
  for (int i = 0; i < 2; ++i)
#pragma unroll
    for (int j = 0; j < 2; ++j) acc[i][j] = (f32x4){0.f, 0.f, 0.f, 0.f};

  float4 a4[4], w4[4], a4n[4], w4n[4];
#pragma unroll
  for (int u = 0; u < 4; ++u) {
    const float4 x1 = *(const float4*)(Ap + u * 4);
    const float4 x2 = *(const float4*)(A2p + u * 4);
    a4[u] = make_float4(x1.x + x2.x, x1.y + x2.y, x1.z + x2.z, x1.w + x2.w);
    w4[u] = *(const float4*)(Wp + u * 4);
  }
  for (int k0 = 0; k0 < 1024; k0 += 64) {
    __syncthreads();
    *(bf16x8*)&As[srow][skc]     = cvt8(a4[0], a4[1]);
    *(bf16x8*)&As[srow][skc + 8] = cvt8(a4[2], a4[3]);
    *(bf16x8*)&Bs[srow][skc]     = cvt8(w4[0], w4[1]);
    *(bf16x8*)&Bs[srow][skc + 8] = cvt8(w4[2], w4[3]);
    __syncthreads();
    if (k0 + 64 < 1024) {
#pragma unroll
      for (int u = 0; u < 4; ++u) {
        const float4 x1 = *(const float4*)(Ap + k0 + 64 + u * 4);
        const float4 x2 = *(const float4*)(A2p + k0 + 64 + u * 4);
        a4n[u] = make_float4(x1.x + x2.x, x1.y + x2.y, x1.z + x2.z, x1.w + x2.w);
        w4n[u] = *(const float4*)(Wp + k0 + 64 + u * 4);
      }
    }
#pragma unroll
    for (int ks = 0; ks < 2; ++ks) {
      bf16x8 af[2], bff[2];
#pragma unroll
      for (int f = 0; f < 2; ++f) {
        af[f]  = *(const bf16x8*)&As[wr * 32 + f * 16 + fr][ks * 32 + kb];
        bff[f] = *(const bf16x8*)&Bs[wc * 32 + f * 16 + fr][ks * 32 + kb];
      }
#pragma unroll
      for (int i = 0; i < 2; ++i)
#pragma unroll
        for (int j = 0; j < 2; ++j)
          acc[i][j] = MFMA16(af[i], bff[j], acc[i][j]);
    }
#pragma unroll
    for (int u = 0; u < 4; ++u) { a4[u] = a4n[u]; w4[u] = w4n[u]; }
  }
  const int lrow = (lane >> 4) << 2, lcol = lane & 15;
#pragma unroll
  for (int i = 0; i < 2; ++i) {
#pragma unroll
    for (int j = 0; j < 2; ++j) {
      const int n = n0 + wc * 32 + j * 16 + lcol;
      const float bvl = bias[n];
#pragma unroll
      for (int r = 0; r < 4; ++r) {
        const int m = m0 + wr * 32 + i * 16 + lrow + r;
        Cf[(size_t)m * 1024 + n] = acc[i][j][r] + bvl;
      }
    }
  }
}

// =====================================================================
extern "C" void kernel_launch(void* const* d_in, const int* in_sizes, int n_in,
                              void* d_out, int out_size, void* d_ws, size_t ws_size,
                              hipStream_t stream)
{
  const float* query = (const float*)d_in[0];
  const float* key   = (const float*)d_in[1];
  const float* value = (const float*)d_in[2];
  const float* rk    = (const float*)d_in[3];
  const float* rv    = (const float*)d_in[4];
  const int*   mask  = (const int*)d_in[5];
  const int*   sep   = (const int*)d_in[6];
  const float* hreg  = (const float*)d_in[7];
  const float* Wq    = (const float*)d_in[8];
  const float* bq    = (const float*)d_in[9];
  const float* Wk    = (const float*)d_in[10];
  const float* bk    = (const float*)d_in[11];
  const float* Wv    = (const float*)d_in[12];
  const float* bv    = (const float*)d_in[13];
  const float* Wo    = (const float*)d_in[14];
  const float* bo    = (const float*)d_in[15];
  const float* hw    = (const float*)d_in[16];
  float* out = (float*)d_out;

  float* ws  = (float*)d_ws;
  float* qb  = ws;                           // 1,048,576 f32
  float* sc  = qb + 1048576;                 // 4,194,304 f32
  float* xa  = sc + 4194304;                 // 1,048,576 f32
  float* xb2 = xa + 1048576;                 // 1,048,576 f32
  float* gb  = xb2 + 1048576;                //     8,192 f32
  bf16* qb16 = (bf16*)(gb + 8192);           // 1,048,576 bf16
  bf16* kb16 = qb16 + 1048576;               // 1,048,576 bf16
  bf16* vt16 = kb16 + 1048576;               // 1,048,576 bf16
  bf16* pb16 = vt16 + 1048576;               // 4,194,304 bf16

  proj3_mfma<<<dim3(256, 3), 256, 0, stream>>>(query, key, value,
                                               Wq, Wk, Wv, bq, bk, bv,
                                               qb, qb16, kb16, vt16);
  qs_fat<<<dim3(1025), 256, 0, stream>>>(qb16, kb16, sc,
                                         qb, hw, sep, hreg, gb, out + 1048576);
  stream_attn<<<dim3(1024), 256, 0, stream>>>(qb, rk, sc, mask, gb, rv,
                                              pb16, xa);
  pv_mfma<<<dim3(16, 16), 256, 0, stream>>>(pb16, vt16, xb2);
  proj_out<<<dim3(256), 256, 0, stream>>>(xa, xb2, Wo, bo, out);
}